// Round 1
// baseline (469.164 us; speedup 1.0000x reference)
//
#include <hip/hip_runtime.h>

// CostVolume2D: N=8, C=128, H=96, W=224, D=4 -> 81 channels.
// out[n, dy*9+dx, h, w] = mean_c f1[n,c,h,w] * f2[n,c,h+dy-4,w+dx-4] (0 if OOB)
//
// Block = 64 threads (1 wave): tile 32(w) x 16(h), one dy-group of 3 dy values.
// Per thread: 4w x 2h pixels, 27 k-channels -> 216 fp32 accumulators.
// f2 tile (18 rows x 40 cols) staged in LDS per channel; f1 read direct from
// global (float4). Next channel's staging loads prefetched into registers
// before the FMA block so the barrier's vmcnt(0) drain is free.

constexpr int Cn = 128;
constexpr int Hh = 96;
constexpr int Ww = 224;
constexpr int HW = Hh * Ww;       // 21504
constexpr int TILE_H = 16;
constexpr int TILE_W = 32;
constexpr int F2R = 18;           // TILE_H + 2 (3 dy span)
constexpr int F2C = 40;           // TILE_W + 8

__global__ __launch_bounds__(64, 1)
void costvol_kernel(const float* __restrict__ f1g, const float* __restrict__ f2g,
                    float* __restrict__ outg) {
    __shared__ float lds[F2R * F2C];   // 720 floats = 2880 B

    const int b   = blockIdx.x;
    const int dyg = b % 3;             // dy group -> dy = 3*dyg + bb
    const int wt  = (b / 3) % 7;
    const int ht  = (b / 21) % 6;
    const int n   = b / 126;

    const int h0 = ht * TILE_H;
    const int w0 = wt * TILE_W;
    const int d0 = dyg * 3;

    const int tid = threadIdx.x;
    const int gx  = tid & 7;           // w-group: pixel w = w0 + 4*gx + px
    const int gy  = tid >> 3;          // h-group: pixel h = h0 + 2*gy + a

    // ---- staging slot precompute: 180 float4 slots cover 18x40 tile ----
    int  sgOff[3];
    int  sgLds[3];
    bool sgAct[3];
    bool sgVal[3];
#pragma unroll
    for (int s = 0; s < 3; ++s) {
        const int idx = s * 64 + tid;          // [0,192)
        const int row = idx / 10;
        const int c4  = idx - row * 10;
        const bool act = (idx < 180);
        const int y  = h0 + d0 - 4 + row;      // global f2 row
        const int xg = w0 - 4 + 4 * c4;        // global f2 col (float4 granule
                                               // never straddles the W border:
                                               // w0 % 32 == 0, W % 4 == 0)
        const bool val = act && (y >= 0) && (y < Hh) && (xg >= 0) && (xg < Ww);
        sgAct[s] = act;
        sgVal[s] = val;
        sgOff[s] = val ? (y * Ww + xg) : 0;
        sgLds[s] = row * F2C + 4 * c4;         // only used when act
    }

    const size_t nbase = (size_t)n * Cn * HW;
    const float* f1n = f1g + nbase;
    const float* f2n = f2g + nbase;

    const int hA = h0 + 2 * gy;
    const int wA = w0 + 4 * gx;
    const int f1off = hA * Ww + wA;

    float4 acc[2][3][9];
#pragma unroll
    for (int a = 0; a < 2; ++a)
#pragma unroll
        for (int bb = 0; bb < 3; ++bb)
#pragma unroll
            for (int dx = 0; dx < 9; ++dx)
                acc[a][bb][dx] = make_float4(0.f, 0.f, 0.f, 0.f);

    const float4 zero4 = make_float4(0.f, 0.f, 0.f, 0.f);

    // prefetch c = 0
    float4 st[3], f1r[2];
    {
#pragma unroll
        for (int s = 0; s < 3; ++s)
            st[s] = sgVal[s] ? *(const float4*)(f2n + sgOff[s]) : zero4;
        const float* f1c = f1n + f1off;
        f1r[0] = *(const float4*)(f1c);
        f1r[1] = *(const float4*)(f1c + Ww);
    }

#pragma unroll 1
    for (int c = 0; c < Cn; ++c) {
        __syncthreads();                       // LDS reads of c-1 complete
#pragma unroll
        for (int s = 0; s < 3; ++s)
            if (sgAct[s]) *(float4*)(&lds[sgLds[s]]) = st[s];
        __syncthreads();

        const float4 fA0 = f1r[0];
        const float4 fA1 = f1r[1];

        // prefetch c+1 (latency hidden behind the 216 FMAs below)
        if (c + 1 < Cn) {
            const float* f2c = f2n + (size_t)(c + 1) * HW;
#pragma unroll
            for (int s = 0; s < 3; ++s)
                st[s] = sgVal[s] ? *(const float4*)(f2c + sgOff[s]) : zero4;
            const float* f1c = f1n + (size_t)(c + 1) * HW + f1off;
            f1r[0] = *(const float4*)(f1c);
            f1r[1] = *(const float4*)(f1c + Ww);
        }

        const int rb = 2 * gy;
#pragma unroll
        for (int r = 0; r < 4; ++r) {
            // f2 window: LDS row rb+r, cols [4gx, 4gx+12) -- 16B aligned
            const float* lr = &lds[(rb + r) * F2C + 4 * gx];
            const float4 q0 = *(const float4*)(lr);
            const float4 q1 = *(const float4*)(lr + 4);
            const float4 q2 = *(const float4*)(lr + 8);
            const float wv[12] = {q0.x, q0.y, q0.z, q0.w,
                                  q1.x, q1.y, q1.z, q1.w,
                                  q2.x, q2.y, q2.z, q2.w};
            // combos (a, bb) with a + bb == r serve this f2 row
#pragma unroll
            for (int a = 0; a < 2; ++a) {
                const int bb = r - a;
                if (bb < 0 || bb > 2) continue;
                const float4 fv = (a == 0) ? fA0 : fA1;
#pragma unroll
                for (int dx = 0; dx < 9; ++dx) {
                    acc[a][bb][dx].x += fv.x * wv[dx + 0];
                    acc[a][bb][dx].y += fv.y * wv[dx + 1];
                    acc[a][bb][dx].z += fv.z * wv[dx + 2];
                    acc[a][bb][dx].w += fv.w * wv[dx + 3];
                }
            }
        }
    }

    // ---- writeout: 2 rows x 27 k x float4, all coalesced 16B stores ----
    const float sc = 1.0f / 128.0f;
    float* ob = outg + (size_t)n * 81 * HW + (size_t)hA * Ww + wA;
#pragma unroll
    for (int a = 0; a < 2; ++a)
#pragma unroll
        for (int bb = 0; bb < 3; ++bb)
#pragma unroll
            for (int dx = 0; dx < 9; ++dx) {
                const int k = (d0 + bb) * 9 + dx;
                float4 v = acc[a][bb][dx];
                v.x *= sc; v.y *= sc; v.z *= sc; v.w *= sc;
                *(float4*)(ob + (size_t)k * HW + a * Ww) = v;
            }
}

extern "C" void kernel_launch(void* const* d_in, const int* in_sizes, int n_in,
                              void* d_out, int out_size, void* d_ws, size_t ws_size,
                              hipStream_t stream) {
    const float* f1 = (const float*)d_in[0];
    const float* f2 = (const float*)d_in[1];
    float* out = (float*)d_out;
    // grid: 8 n * 6 h-tiles * 7 w-tiles * 3 dy-groups = 1008 blocks of 1 wave
    costvol_kernel<<<dim3(1008), dim3(64), 0, stream>>>(f1, f2, out);
}

// Round 2
// 290.324 us; speedup vs baseline: 1.6160x; 1.6160x over previous
//
#include <hip/hip_runtime.h>

// CostVolume2D: N=8, C=128, H=96, W=224, D=4 -> 81 channels.
// out[n, dy*9+dx, h, w] = mean_c f1[n,c,h,w] * f2[n,c,h+dy-4,w+dx-4] (0 if OOB)
//
// Block = 192 threads (3 waves), tile 32(w) x 16(h). Wave wb handles
// dy = 3*dyg + wb (one dy per wave -> 9 dx channels). Per thread: 8w x 1h
// pixels x 9 dx = 72 fp32 accumulators (NO spill; round-1's 216-acc layout
// spilled at VGPR_Count=132 and ran 7x slow).
// f2 tile (18 rows x 40 cols, stride 44 for conflict-free b128 reads) staged
// in LDS per channel, shared by all 3 waves. f1 read direct from global.
// Next channel's loads prefetched into registers before the FMA block.

constexpr int Cn = 128;
constexpr int Hh = 96;
constexpr int Ww = 224;
constexpr int HW = Hh * Ww;       // 21504
constexpr int TILE_H = 16;
constexpr int TILE_W = 32;
constexpr int F2R = 18;           // TILE_H + 2 (3 dy span)
constexpr int F2S = 44;           // row stride (floats): 40 used + 4 pad
                                  // 44*4B=176B; 176 mod 128 = 48 = 16*3 ->
                                  // addr mod 128B = 16*((3gy+2gx) mod 8):
                                  // 8 lanes per 16B seg -> conflict-free b128

__global__ __launch_bounds__(192, 3)
void costvol_kernel(const float* __restrict__ f1g, const float* __restrict__ f2g,
                    float* __restrict__ outg) {
    __shared__ float lds[F2R * F2S];   // 792 floats = 3168 B

    const int b   = blockIdx.x;
    const int dyg = b % 3;             // dy = 3*dyg + wb
    const int wt  = (b / 3) % 7;
    const int ht  = (b / 21) % 6;
    const int n   = b / 126;

    const int h0 = ht * TILE_H;
    const int w0 = wt * TILE_W;
    const int d0 = dyg * 3;

    const int tid  = threadIdx.x;
    const int wb   = tid >> 6;         // wave id = dy offset in group
    const int lane = tid & 63;
    const int gx   = lane & 3;         // 8 w px: w = w0 + 8*gx + (0..7)
    const int gy   = lane >> 2;        // h row: h = h0 + gy

    // ---- staging: 180 float4 slots cover 18 rows x 10 groups ----
    const int  srow = tid / 10;
    const int  sg   = tid - srow * 10;
    const bool sAct = (tid < 180);
    const int  yS   = h0 + d0 - 4 + srow;     // global f2 row
    const int  xS   = w0 - 4 + 4 * sg;        // global f2 col (float4 granule
                                              // never straddles W border)
    const bool sVal = sAct && (yS >= 0) && (yS < Hh) && (xS >= 0) && (xS < Ww);
    const int  sOff = sVal ? (yS * Ww + xS) : 0;
    const int  sLds = srow * F2S + 4 * sg;

    const size_t nbase = (size_t)n * Cn * HW;
    const float* f1n = f1g + nbase;
    const float* f2n = f2g + nbase;

    const int hA    = h0 + gy;
    const int wA    = w0 + 8 * gx;
    const int f1off = hA * Ww + wA;
    const int ldsr  = (gy + wb) * F2S + 8 * gx;   // window: 16 floats, 4 b128

    float4 acc[2][9];
#pragma unroll
    for (int p = 0; p < 2; ++p)
#pragma unroll
        for (int dx = 0; dx < 9; ++dx)
            acc[p][dx] = make_float4(0.f, 0.f, 0.f, 0.f);

    const float4 zero4 = make_float4(0.f, 0.f, 0.f, 0.f);

    // prefetch c = 0
    float4 st, f1r0, f1r1;
    st   = sVal ? *(const float4*)(f2n + sOff) : zero4;
    f1r0 = *(const float4*)(f1n + f1off);
    f1r1 = *(const float4*)(f1n + f1off + 4);

#pragma unroll 1
    for (int c = 0; c < Cn; ++c) {
        __syncthreads();                       // LDS reads of c-1 complete
        if (sAct) *(float4*)(&lds[sLds]) = st;
        __syncthreads();

        const float4 a0 = f1r0;
        const float4 a1 = f1r1;

        // prefetch c+1 (latency hidden behind the 72 FMAs below)
        if (c + 1 < Cn) {
            const float* f2c = f2n + (size_t)(c + 1) * HW;
            st = sVal ? *(const float4*)(f2c + sOff) : zero4;
            const float* f1c = f1n + (size_t)(c + 1) * HW + f1off;
            f1r0 = *(const float4*)(f1c);
            f1r1 = *(const float4*)(f1c + 4);
        }

        // f2 window: row gy+wb, cols [8gx, 8gx+16) -- 4 aligned b128
        const float* lr = &lds[ldsr];
        const float4 q0 = *(const float4*)(lr);
        const float4 q1 = *(const float4*)(lr + 4);
        const float4 q2 = *(const float4*)(lr + 8);
        const float4 q3 = *(const float4*)(lr + 12);
        const float wv[16] = {q0.x, q0.y, q0.z, q0.w,
                              q1.x, q1.y, q1.z, q1.w,
                              q2.x, q2.y, q2.z, q2.w,
                              q3.x, q3.y, q3.z, q3.w};

        // px w = 8gx + 4p + j needs f2 col (w-4+dx) -> wv[4p + dx + j]
#pragma unroll
        for (int dx = 0; dx < 9; ++dx) {
            acc[0][dx].x += a0.x * wv[dx + 0];
            acc[0][dx].y += a0.y * wv[dx + 1];
            acc[0][dx].z += a0.z * wv[dx + 2];
            acc[0][dx].w += a0.w * wv[dx + 3];
            acc[1][dx].x += a1.x * wv[dx + 4];
            acc[1][dx].y += a1.y * wv[dx + 5];
            acc[1][dx].z += a1.z * wv[dx + 6];
            acc[1][dx].w += a1.w * wv[dx + 7];
        }
    }

    // ---- writeout: 2 x 9 float4 per thread, coalesced 16B stores ----
    const float sc = 1.0f / 128.0f;
    const int dy = d0 + wb;
    float* ob = outg + (size_t)n * 81 * HW + (size_t)hA * Ww + wA;
#pragma unroll
    for (int dx = 0; dx < 9; ++dx) {
        const int k = dy * 9 + dx;
#pragma unroll
        for (int p = 0; p < 2; ++p) {
            float4 v = acc[p][dx];
            v.x *= sc; v.y *= sc; v.z *= sc; v.w *= sc;
            *(float4*)(ob + (size_t)k * HW + 4 * p) = v;
        }
    }
}

extern "C" void kernel_launch(void* const* d_in, const int* in_sizes, int n_in,
                              void* d_out, int out_size, void* d_ws, size_t ws_size,
                              hipStream_t stream) {
    const float* f1 = (const float*)d_in[0];
    const float* f2 = (const float*)d_in[1];
    float* out = (float*)d_out;
    // grid: 8 n * 6 h-tiles * 7 w-tiles * 3 dy-groups = 1008 blocks of 3 waves
    costvol_kernel<<<dim3(1008), dim3(192), 0, stream>>>(f1, f2, out);
}